// Round 3
// baseline (507.258 us; speedup 1.0000x reference)
//
#include <hip/hip_runtime.h>
#include <math.h>

#define NG 4096
#define M 50
#define KTOP 30
#define H 32
#define F_IN 128
#define EPG 400          // edges per graph (M * DEG)
#define E_TOTAL (NG * EPG)
#define DLAT 97
#define LATS 100         // padded stride for lat tile (keeps 16B alignment)
#define NTHREADS 256

// fast tanh: 1 - 2/(e^{2x}+1). __expf -> v_exp_f32; clamp avoids inf/NaN.
// abs err ~1e-6 -- used for layers 1-3 only; layer 4 (sort key) uses tanhf.
__device__ __forceinline__ float fast_tanh(float x) {
    x = fminf(fmaxf(x, -15.f), 15.f);
    float e = __expf(2.f * x);
    return 1.f - 2.f / (e + 1.f);
}

// -------- GCN matmul ------------------------------------------------------
// tbuf[i][j] = sum_k hin[i*istride+k] * W[k*H+j]
// thread (iset = tid>>5, j = tid&31) owns a contiguous row block:
// isets 0,1 -> 7 rows; isets 2..7 -> 6 rows (exactly 50, no wasted rows).
// The `seven` branch is wave-uniform (wave0 = isets {0,1}).
template <int KIN>
__device__ __forceinline__ void gcn_matmul(const float* hin, int istride,
                                           const float* __restrict__ W,
                                           float (*tb)[H], int tid) {
    const int j = tid & 31, iset = tid >> 5;
    const bool seven = (iset < 2);
    const int base = seven ? 7 * iset : 14 + 6 * (iset - 2);
    float acc[7];
#pragma unroll
    for (int r = 0; r < 7; r++) acc[r] = 0.f;
#pragma unroll 2
    for (int k4 = 0; k4 < KIN / 4; k4++) {
        const float w0 = W[(4 * k4 + 0) * H + j];
        const float w1 = W[(4 * k4 + 1) * H + j];
        const float w2 = W[(4 * k4 + 2) * H + j];
        const float w3 = W[(4 * k4 + 3) * H + j];
#pragma unroll
        for (int r = 0; r < 6; r++) {
            const float4 xv = *(const float4*)(hin + (base + r) * istride + 4 * k4);
            acc[r] += xv.x * w0 + xv.y * w1 + xv.z * w2 + xv.w * w3;
        }
        if (seven) {
            const float4 xv = *(const float4*)(hin + (base + 6) * istride + 4 * k4);
            acc[6] += xv.x * w0 + xv.y * w1 + xv.z * w2 + xv.w * w3;
        }
    }
#pragma unroll
    for (int r = 0; r < 6; r++) tb[base + r][j] = acc[r];
    if (seven) tb[base + 6][j] = acc[6];
}

// aggregation + bias + tanh -> lat[:, col0:col0+32]
__device__ __forceinline__ void gcn_agg(const float (*tbuf)[H], const float* __restrict__ b,
                                        float (*lat)[LATS], int col0,
                                        const float* dinv, const int* csr_off,
                                        const unsigned char* csr_src, const float* csr_nrm,
                                        int tid) {
    const int j = tid & 31, iset = tid >> 5;
    for (int i = iset; i < M; i += 8) {
        float acc = tbuf[i][j] * dinv[i] * dinv[i];   // self loop: norm = 1/deg
        int e0 = csr_off[i], e1 = csr_off[i + 1];
        for (int e = e0; e < e1; e++)
            acc += tbuf[csr_src[e]][j] * csr_nrm[e];
        lat[i][col0 + j] = fast_tanh(acc + b[j]);
    }
}

__global__ __launch_bounds__(NTHREADS, 5)
void dgcnn_kernel(const float* __restrict__ x, const int* __restrict__ eidx,
                  const float* __restrict__ W0, const float* __restrict__ b0,
                  const float* __restrict__ W1, const float* __restrict__ b1,
                  const float* __restrict__ W2, const float* __restrict__ b2,
                  const float* __restrict__ W3, const float* __restrict__ b3,
                  const float* __restrict__ C1w, const float* __restrict__ C1b,
                  const float* __restrict__ C2w, const float* __restrict__ C2b,
                  const float* __restrict__ L1w, const float* __restrict__ L1b,
                  const float* __restrict__ L2w, const float* __restrict__ L2b,
                  float* __restrict__ out) {
    // LDS total ~32.4 KB -> 5 blocks/CU (20 waves, 62.5% occupancy cap).
    __shared__ __align__(16) float lat[M][LATS];   // 20000 B: h1|h2|h3|h4
    __shared__ float tbuf[M][H];                   //  6400 B: pre-agg h@W
    __shared__ float csr_nrm[EPG];                 //  1600 B
    __shared__ unsigned char csr_src[EPG];         //   400 B (node ids < 50)
    __shared__ int   csr_off[M + 1];               //   204 B
    __shared__ int   degi[M];                      //   200 B (reused as cursor)
    __shared__ float dinv[M];                      //   200 B
    __shared__ struct Post {                       //  3392 B tail (phase union)
        float pbuf[16][15];
        union {
            struct { float z1[16][KTOP]; int ord[M]; } a;
            struct { float z2[352]; float red[256]; } b;
        } u;
    } post;

    const int g = blockIdx.x;
    const int tid = threadIdx.x;
    const int nbase = g * M;
    const int ebase = g * EPG;
    const float* xg = x + (size_t)nbase * F_IN;

    // ---- degrees (in-degree + self loop) ----
    if (tid < M) degi[tid] = 1;
    __syncthreads();
    for (int e = tid; e < EPG; e += NTHREADS) {
        int d = eidx[E_TOTAL + ebase + e] - nbase;
        atomicAdd(&degi[d], 1);
    }
    // ---- GCN layer-1 matmul (independent of edge work; overlaps it) ----
    gcn_matmul<F_IN>(xg, F_IN, W0, tbuf, tid);
    __syncthreads();                       // degi + tbuf complete
    // ---- dinv, CSR offsets (wave-0 shuffle scan), cursor=degi ----
    if (tid < M) dinv[tid] = rsqrtf((float)degi[tid]);
    if (tid < 64) {
        int cnt = (tid < M) ? (degi[tid] - 1) : 0;
        int incl = cnt;
#pragma unroll
        for (int off = 1; off < 64; off <<= 1) {
            int nv = __shfl_up(incl, off);
            if (tid >= off) incl += nv;
        }
        if (tid < M) { csr_off[tid] = incl - cnt; degi[tid] = incl - cnt; }
        if (tid == M - 1) csr_off[M] = incl;
    }
    __syncthreads();
    // ---- CSR fill (by dst); re-read eidx (L2-hot) ----
    for (int e = tid; e < EPG; e += NTHREADS) {
        int s = eidx[ebase + e] - nbase;
        int d = eidx[E_TOTAL + ebase + e] - nbase;
        float nr = dinv[s] * dinv[d];
        int pos = atomicAdd(&degi[d], 1);
        csr_src[pos] = (unsigned char)s;
        csr_nrm[pos] = nr;
    }
    __syncthreads();

    // ---- layer 1 agg -> lat[:,0:32] ----
    gcn_agg(tbuf, b0, lat, 0, dinv, csr_off, csr_src, csr_nrm, tid);
    __syncthreads();
    // ---- layer 2 ----
    gcn_matmul<H>(&lat[0][0], LATS, W1, tbuf, tid);
    __syncthreads();
    gcn_agg(tbuf, b1, lat, 32, dinv, csr_off, csr_src, csr_nrm, tid);
    __syncthreads();
    // ---- layer 3 ----
    gcn_matmul<H>(&lat[0][32], LATS, W2, tbuf, tid);
    __syncthreads();
    gcn_agg(tbuf, b2, lat, 64, dinv, csr_off, csr_src, csr_nrm, tid);
    __syncthreads();
    // ---- layer 4 (H -> 1): exact tanhf (sort key) ----
    if (tid < M) {
        float acc = 0.f;
        for (int k = 0; k < H; k++) acc += lat[tid][64 + k] * W3[k];
        tbuf[tid][0] = acc;
    }
    __syncthreads();
    if (tid < M) {
        float acc = tbuf[tid][0] * dinv[tid] * dinv[tid];
        int e0 = csr_off[tid], e1 = csr_off[tid + 1];
        for (int e = e0; e < e1; e++)
            acc += tbuf[csr_src[e]][0] * csr_nrm[e];
        lat[tid][96] = tanhf(acc + b3[0]);
    }
    __syncthreads();

    // ---- sort-pool: stable descending rank over lat[:,96] ----
    if (tid < M) {
        float v = lat[tid][96];
        int r = 0;
        for (int jj = 0; jj < M; jj++) {
            float vj = lat[jj][96];
            r += (vj > v) || (vj == v && jj < tid);
        }
        post.u.a.ord[r] = tid;
    }
    __syncthreads();

    // ---- Conv1d(1,16,97,stride 97) + ReLU ----
    // lane map t=idx>>4: 16 lanes share one row -> LDS broadcast, no conflicts
    for (int idx = tid; idx < 16 * KTOP; idx += NTHREADS) {
        int t = idx >> 4, c = idx & 15;
        const float* row = lat[post.u.a.ord[t]];
        float acc = 0.f;
        for (int d = 0; d < DLAT; d++) acc += row[d] * C1w[c * DLAT + d];
        acc += C1b[c];
        post.u.a.z1[c][t] = fmaxf(acc, 0.f);
    }
    __syncthreads();

    // ---- MaxPool1d(2,2) -> pbuf (outside union) ----
    for (int idx = tid; idx < 16 * 15; idx += NTHREADS) {
        int c = idx / 15, t = idx - c * 15;
        post.pbuf[c][t] = fmaxf(post.u.a.z1[c][2 * t], post.u.a.z1[c][2 * t + 1]);
    }
    __syncthreads();

    // ---- Conv1d(16,32,5) + ReLU, flatten f = o*11 + t (z1/ord now dead) ----
    for (int idx = tid; idx < 352; idx += NTHREADS) {
        int o = idx / 11, t = idx - o * 11;
        float acc = C2b[o];
        for (int i = 0; i < 16; i++) {
#pragma unroll
            for (int k = 0; k < 5; k++)
                acc += post.pbuf[i][t + k] * C2w[(o * 16 + i) * 5 + k];
        }
        post.u.b.z2[idx] = fmaxf(acc, 0.f);
    }
    __syncthreads();

    // ---- Dense 352 -> 128 + ReLU (split over 256 threads) ----
    {
        int jj = tid & 127, half = tid >> 7;
        float acc = (half == 0) ? L1b[jj] : 0.f;
        int f0 = half * 176;
        for (int f = f0; f < f0 + 176; f++)
            acc += post.u.b.z2[f] * L1w[f * 128 + jj];
        post.u.b.red[tid] = acc;
    }
    __syncthreads();
    // ---- fuse ReLU + Dense 128 -> 1 (each tid touches only red[tid]) ----
    if (tid < 128)
        post.u.b.red[tid] = fmaxf(post.u.b.red[tid] + post.u.b.red[tid + 128], 0.f)
                            * L2w[tid];
    __syncthreads();
    if (tid < 64) {
        float v = post.u.b.red[tid] + post.u.b.red[tid + 64];
#pragma unroll
        for (int off = 32; off >= 1; off >>= 1)
            v += __shfl_down(v, off);
        if (tid == 0) out[g] = v + L2b[0];
    }
}

extern "C" void kernel_launch(void* const* d_in, const int* in_sizes, int n_in,
                              void* d_out, int out_size, void* d_ws, size_t ws_size,
                              hipStream_t stream) {
    const float* x    = (const float*)d_in[0];
    const int*   eidx = (const int*)d_in[1];
    // d_in[2] (batch) unused: graphs are contiguous equal-size blocks
    dgcnn_kernel<<<NG, NTHREADS, 0, stream>>>(
        x, eidx,
        (const float*)d_in[3],  (const float*)d_in[4],
        (const float*)d_in[5],  (const float*)d_in[6],
        (const float*)d_in[7],  (const float*)d_in[8],
        (const float*)d_in[9],  (const float*)d_in[10],
        (const float*)d_in[11], (const float*)d_in[12],
        (const float*)d_in[13], (const float*)d_in[14],
        (const float*)d_in[15], (const float*)d_in[16],
        (const float*)d_in[17], (const float*)d_in[18],
        (float*)d_out);
}

// Round 4
// 481.627 us; speedup vs baseline: 1.0532x; 1.0532x over previous
//
#include <hip/hip_runtime.h>
#include <math.h>

#define NG 4096
#define M 50
#define KTOP 30
#define H 32
#define F_IN 128
#define EPG 400          // edges per graph (M * DEG)
#define E_TOTAL (NG * EPG)
#define DLAT 97
#define LATS 100         // padded stride for lat tile (keeps 16B alignment)
#define NTHREADS 256

// fast tanh: 1 - 2/(e^{2x}+1). __expf -> v_exp_f32; clamp avoids inf/NaN.
// abs err ~1e-6 -- used for layers 1-3 only; layer 4 (sort key) uses tanhf.
__device__ __forceinline__ float fast_tanh(float x) {
    x = fminf(fmaxf(x, -15.f), 15.f);
    float e = __expf(2.f * x);
    return 1.f - 2.f / (e + 1.f);
}

// -------- GCN matmul ------------------------------------------------------
// tbuf[i][j] = sum_k hin[i*istride+k] * W[k*H+j]
// thread (iset = tid>>5, j = tid&31) owns a contiguous row block:
// isets 0,1 -> 7 rows; isets 2..7 -> 6 rows (exactly 50, no wasted rows).
// The `seven` branch is wave-uniform (wave0 = isets {0,1}).
template <int KIN>
__device__ __forceinline__ void gcn_matmul(const float* hin, int istride,
                                           const float* __restrict__ W,
                                           float (*tb)[H], int tid) {
    const int j = tid & 31, iset = tid >> 5;
    const bool seven = (iset < 2);
    const int base = seven ? 7 * iset : 14 + 6 * (iset - 2);
    float acc[7];
#pragma unroll
    for (int r = 0; r < 7; r++) acc[r] = 0.f;
#pragma unroll 2
    for (int k4 = 0; k4 < KIN / 4; k4++) {
        const float w0 = W[(4 * k4 + 0) * H + j];
        const float w1 = W[(4 * k4 + 1) * H + j];
        const float w2 = W[(4 * k4 + 2) * H + j];
        const float w3 = W[(4 * k4 + 3) * H + j];
#pragma unroll
        for (int r = 0; r < 6; r++) {
            const float4 xv = *(const float4*)(hin + (base + r) * istride + 4 * k4);
            acc[r] += xv.x * w0 + xv.y * w1 + xv.z * w2 + xv.w * w3;
        }
        if (seven) {
            const float4 xv = *(const float4*)(hin + (base + 6) * istride + 4 * k4);
            acc[6] += xv.x * w0 + xv.y * w1 + xv.z * w2 + xv.w * w3;
        }
    }
#pragma unroll
    for (int r = 0; r < 6; r++) tb[base + r][j] = acc[r];
    if (seven) tb[base + 6][j] = acc[6];
}

// aggregation + bias + tanh -> lat[:, col0:col0+32]
__device__ __forceinline__ void gcn_agg(const float (*tbuf)[H], const float* __restrict__ b,
                                        float (*lat)[LATS], int col0,
                                        const float* dinv, const int* csr_off,
                                        const unsigned char* csr_src, const float* csr_nrm,
                                        int tid) {
    const int j = tid & 31, iset = tid >> 5;
    for (int i = iset; i < M; i += 8) {
        float acc = tbuf[i][j] * dinv[i] * dinv[i];   // self loop: norm = 1/deg
        int e0 = csr_off[i], e1 = csr_off[i + 1];
        for (int e = e0; e < e1; e++)
            acc += tbuf[csr_src[e]][j] * csr_nrm[e];
        lat[i][col0 + j] = fast_tanh(acc + b[j]);
    }
}

// launch_bounds(256,4): empirically the spill-free point (64 VGPR, zero
// scratch). (256,5) made the allocator clamp to 48 VGPR -> 70 MB of spill
// traffic (round-3 regression). Occupancy is LDS-capped at 5 blocks/CU.
__global__ __launch_bounds__(NTHREADS, 4)
void dgcnn_kernel(const float* __restrict__ x, const int* __restrict__ eidx,
                  const float* __restrict__ W0, const float* __restrict__ b0,
                  const float* __restrict__ W1, const float* __restrict__ b1,
                  const float* __restrict__ W2, const float* __restrict__ b2,
                  const float* __restrict__ W3, const float* __restrict__ b3,
                  const float* __restrict__ C1w, const float* __restrict__ C1b,
                  const float* __restrict__ C2w, const float* __restrict__ C2b,
                  const float* __restrict__ L1w, const float* __restrict__ L1b,
                  const float* __restrict__ L2w, const float* __restrict__ L2b,
                  float* __restrict__ out) {
    // LDS total ~32.4 KB -> 5 blocks/CU (20 waves, 62.5% occupancy cap).
    __shared__ __align__(16) float lat[M][LATS];   // 20000 B: h1|h2|h3|h4
    __shared__ float tbuf[M][H];                   //  6400 B: pre-agg h@W
    __shared__ float csr_nrm[EPG];                 //  1600 B
    __shared__ unsigned char csr_src[EPG];         //   400 B (node ids < 50)
    __shared__ int   csr_off[M + 1];               //   204 B
    __shared__ int   degi[M];                      //   200 B (reused as cursor)
    __shared__ float dinv[M];                      //   200 B
    __shared__ struct Post {                       //  3392 B tail (phase union)
        float pbuf[16][15];
        union {
            struct { float z1[16][KTOP]; int ord[M]; } a;
            struct { float z2[352]; float red[256]; } b;
        } u;
    } post;

    const int g = blockIdx.x;
    const int tid = threadIdx.x;
    const int nbase = g * M;
    const int ebase = g * EPG;
    const float* xg = x + (size_t)nbase * F_IN;

    // ---- degrees (in-degree + self loop) ----
    if (tid < M) degi[tid] = 1;
    __syncthreads();
    for (int e = tid; e < EPG; e += NTHREADS) {
        int d = eidx[E_TOTAL + ebase + e] - nbase;
        atomicAdd(&degi[d], 1);
    }
    // ---- GCN layer-1 matmul (independent of edge work; overlaps it) ----
    gcn_matmul<F_IN>(xg, F_IN, W0, tbuf, tid);
    __syncthreads();                       // degi + tbuf complete
    // ---- dinv, CSR offsets (wave-0 shuffle scan), cursor=degi ----
    if (tid < M) dinv[tid] = rsqrtf((float)degi[tid]);
    if (tid < 64) {
        int cnt = (tid < M) ? (degi[tid] - 1) : 0;
        int incl = cnt;
#pragma unroll
        for (int off = 1; off < 64; off <<= 1) {
            int nv = __shfl_up(incl, off);
            if (tid >= off) incl += nv;
        }
        if (tid < M) { csr_off[tid] = incl - cnt; degi[tid] = incl - cnt; }
        if (tid == M - 1) csr_off[M] = incl;
    }
    __syncthreads();
    // ---- CSR fill (by dst); re-read eidx (L2-hot) ----
    for (int e = tid; e < EPG; e += NTHREADS) {
        int s = eidx[ebase + e] - nbase;
        int d = eidx[E_TOTAL + ebase + e] - nbase;
        float nr = dinv[s] * dinv[d];
        int pos = atomicAdd(&degi[d], 1);
        csr_src[pos] = (unsigned char)s;
        csr_nrm[pos] = nr;
    }
    __syncthreads();

    // ---- layer 1 agg -> lat[:,0:32] ----
    gcn_agg(tbuf, b0, lat, 0, dinv, csr_off, csr_src, csr_nrm, tid);
    __syncthreads();
    // ---- layer 2 ----
    gcn_matmul<H>(&lat[0][0], LATS, W1, tbuf, tid);
    __syncthreads();
    gcn_agg(tbuf, b1, lat, 32, dinv, csr_off, csr_src, csr_nrm, tid);
    __syncthreads();
    // ---- layer 3 ----
    gcn_matmul<H>(&lat[0][32], LATS, W2, tbuf, tid);
    __syncthreads();
    gcn_agg(tbuf, b2, lat, 64, dinv, csr_off, csr_src, csr_nrm, tid);
    __syncthreads();
    // ---- layer 4 (H -> 1): exact tanhf (sort key) ----
    if (tid < M) {
        float acc = 0.f;
        for (int k = 0; k < H; k++) acc += lat[tid][64 + k] * W3[k];
        tbuf[tid][0] = acc;
    }
    __syncthreads();
    if (tid < M) {
        float acc = tbuf[tid][0] * dinv[tid] * dinv[tid];
        int e0 = csr_off[tid], e1 = csr_off[tid + 1];
        for (int e = e0; e < e1; e++)
            acc += tbuf[csr_src[e]][0] * csr_nrm[e];
        lat[tid][96] = tanhf(acc + b3[0]);
    }
    __syncthreads();

    // ---- sort-pool: stable descending rank over lat[:,96] ----
    if (tid < M) {
        float v = lat[tid][96];
        int r = 0;
        for (int jj = 0; jj < M; jj++) {
            float vj = lat[jj][96];
            r += (vj > v) || (vj == v && jj < tid);
        }
        post.u.a.ord[r] = tid;
    }
    __syncthreads();

    // ---- Conv1d(1,16,97,stride 97) + ReLU ----
    // lane map t=idx>>4: 16 lanes share one row -> LDS broadcast, no conflicts
    for (int idx = tid; idx < 16 * KTOP; idx += NTHREADS) {
        int t = idx >> 4, c = idx & 15;
        const float* row = lat[post.u.a.ord[t]];
        float acc = 0.f;
        for (int d = 0; d < DLAT; d++) acc += row[d] * C1w[c * DLAT + d];
        acc += C1b[c];
        post.u.a.z1[c][t] = fmaxf(acc, 0.f);
    }
    __syncthreads();

    // ---- MaxPool1d(2,2) -> pbuf (outside union) ----
    for (int idx = tid; idx < 16 * 15; idx += NTHREADS) {
        int c = idx / 15, t = idx - c * 15;
        post.pbuf[c][t] = fmaxf(post.u.a.z1[c][2 * t], post.u.a.z1[c][2 * t + 1]);
    }
    __syncthreads();

    // ---- Conv1d(16,32,5) + ReLU, flatten f = o*11 + t (z1/ord now dead) ----
    for (int idx = tid; idx < 352; idx += NTHREADS) {
        int o = idx / 11, t = idx - o * 11;
        float acc = C2b[o];
        for (int i = 0; i < 16; i++) {
#pragma unroll
            for (int k = 0; k < 5; k++)
                acc += post.pbuf[i][t + k] * C2w[(o * 16 + i) * 5 + k];
        }
        post.u.b.z2[idx] = fmaxf(acc, 0.f);
    }
    __syncthreads();

    // ---- Dense 352 -> 128 + ReLU (split over 256 threads) ----
    {
        int jj = tid & 127, half = tid >> 7;
        float acc = (half == 0) ? L1b[jj] : 0.f;
        int f0 = half * 176;
        for (int f = f0; f < f0 + 176; f++)
            acc += post.u.b.z2[f] * L1w[f * 128 + jj];
        post.u.b.red[tid] = acc;
    }
    __syncthreads();
    // ---- fuse ReLU + Dense 128 -> 1 (each tid touches only red[tid]) ----
    if (tid < 128)
        post.u.b.red[tid] = fmaxf(post.u.b.red[tid] + post.u.b.red[tid + 128], 0.f)
                            * L2w[tid];
    __syncthreads();
    if (tid < 64) {
        float v = post.u.b.red[tid] + post.u.b.red[tid + 64];
#pragma unroll
        for (int off = 32; off >= 1; off >>= 1)
            v += __shfl_down(v, off);
        if (tid == 0) out[g] = v + L2b[0];
    }
}

extern "C" void kernel_launch(void* const* d_in, const int* in_sizes, int n_in,
                              void* d_out, int out_size, void* d_ws, size_t ws_size,
                              hipStream_t stream) {
    const float* x    = (const float*)d_in[0];
    const int*   eidx = (const int*)d_in[1];
    // d_in[2] (batch) unused: graphs are contiguous equal-size blocks
    dgcnn_kernel<<<NG, NTHREADS, 0, stream>>>(
        x, eidx,
        (const float*)d_in[3],  (const float*)d_in[4],
        (const float*)d_in[5],  (const float*)d_in[6],
        (const float*)d_in[7],  (const float*)d_in[8],
        (const float*)d_in[9],  (const float*)d_in[10],
        (const float*)d_in[11], (const float*)d_in[12],
        (const float*)d_in[13], (const float*)d_in[14],
        (const float*)d_in[15], (const float*)d_in[16],
        (const float*)d_in[17], (const float*)d_in[18],
        (float*)d_out);
}

// Round 5
// 425.656 us; speedup vs baseline: 1.1917x; 1.1315x over previous
//
#include <hip/hip_runtime.h>
#include <math.h>

#define NG 4096
#define M 50
#define KTOP 30
#define H 32
#define F_IN 128
#define EPG 400          // edges per graph (M * DEG)
#define PADE 552         // EPG + M*3: CSR rows padded to multiples of 4
#define E_TOTAL (NG * EPG)
#define DLAT 97
#define LATS 100         // padded stride for lat tile (keeps 16B alignment)
#define NTHREADS 256

// fast tanh: 1 - 2/(e^{2x}+1). abs err ~1e-6; layers 1-3 only (layer 4 =
// sort key uses exact tanhf).
__device__ __forceinline__ float fast_tanh(float x) {
    x = fminf(fmaxf(x, -15.f), 15.f);
    float e = __expf(2.f * x);
    return 1.f - 2.f / (e + 1.f);
}

// -------- GCN matmul (round-2 form: straight-line, max load batching) -----
// tbuf[i][j] = sum_k hin[i*istride+k] * W[k*H+j]
// thread (iset = tid>>5, j = tid&31) owns rows {iset, iset+8, ..., iset+48};
// row 49 is recomputed by 6 threads (clamp) — keeps the k4 body branch-free
// so the compiler batches 7 independent float4 loads per iteration.
template <int KIN>
__device__ __forceinline__ void gcn_matmul(const float* hin, int istride,
                                           const float* __restrict__ W,
                                           float (*tb)[H], int tid) {
    const int j = tid & 31, iset = tid >> 5;
    float acc[7];
    int rows[7];
#pragma unroll
    for (int r = 0; r < 7; r++) {
        acc[r] = 0.f;
        int i = iset + r * 8;
        rows[r] = (i >= M) ? (M - 1) : i;
    }
#pragma unroll 2
    for (int k4 = 0; k4 < KIN / 4; k4++) {
        const float w0 = W[(4 * k4 + 0) * H + j];
        const float w1 = W[(4 * k4 + 1) * H + j];
        const float w2 = W[(4 * k4 + 2) * H + j];
        const float w3 = W[(4 * k4 + 3) * H + j];
#pragma unroll
        for (int r = 0; r < 7; r++) {
            const float4 xv = *(const float4*)(hin + rows[r] * istride + 4 * k4);
            acc[r] += xv.x * w0 + xv.y * w1 + xv.z * w2 + xv.w * w3;
        }
    }
#pragma unroll
    for (int r = 0; r < 7; r++) {
        int i = iset + r * 8;
        if (i < M) tb[i][j] = acc[r];
    }
}

// aggregation + bias + tanh. Padded CSR: each row's extent is a multiple of
// 4; one u32 load gives 4 packed u8 src ids, one b128 gives 4 norms, then 4
// INDEPENDENT tbuf reads — 4x shorter dependent-LDS chain than scalar form.
__device__ __forceinline__ void gcn_agg(const float (*tbuf)[H], const float* __restrict__ b,
                                        float (*lat)[LATS], int col0,
                                        const float* dinv, const unsigned short* csr_off,
                                        const unsigned char* csr_src, const float* csr_nrm,
                                        int tid) {
    const int j = tid & 31, iset = tid >> 5;
    for (int i = iset; i < M; i += 8) {
        float acc = tbuf[i][j] * dinv[i] * dinv[i];   // self loop: norm = 1/deg
        int e0 = csr_off[i], e1 = csr_off[i + 1];
        for (int e = e0; e < e1; e += 4) {
            unsigned sp = *(const unsigned*)(csr_src + e);
            float4 nr = *(const float4*)(csr_nrm + e);
            acc += tbuf[sp & 255][j] * nr.x;
            acc += tbuf[(sp >> 8) & 255][j] * nr.y;
            acc += tbuf[(sp >> 16) & 255][j] * nr.z;
            acc += tbuf[sp >> 24][j] * nr.w;
        }
        lat[i][col0 + j] = fast_tanh(acc + b[j]);
    }
}

// (256,4): empirically the spill-free point (64 VGPR). (256,5) clamps the
// allocator to 48 VGPR -> 70 MB scratch spill (round-3 regression).
__global__ __launch_bounds__(NTHREADS, 4)
void dgcnn_kernel(const float* __restrict__ x, const int* __restrict__ eidx,
                  const float* __restrict__ W0, const float* __restrict__ b0,
                  const float* __restrict__ W1, const float* __restrict__ b1,
                  const float* __restrict__ W2, const float* __restrict__ b2,
                  const float* __restrict__ W3, const float* __restrict__ b3,
                  const float* __restrict__ C1w, const float* __restrict__ C1b,
                  const float* __restrict__ C2w, const float* __restrict__ C2b,
                  const float* __restrict__ L1w, const float* __restrict__ L1b,
                  const float* __restrict__ L2w, const float* __restrict__ L2b,
                  float* __restrict__ out) {
    // LDS total ~32.6 KB -- MUST stay <= 32768 B for 5 blocks/CU (5*32K=160K).
    __shared__ __align__(16) float lat[M][LATS];   // 20000 B
    __shared__ float tbuf[M][H];                   //  6400 B
    __shared__ __align__(16) float csr_nrm[PADE];  //  2208 B
    __shared__ unsigned char csr_src[PADE];        //   552 B
    __shared__ unsigned short csr_off[M + 2];      //   104 B
    __shared__ int   degi[M];                      //   200 B (becomes cursor)
    __shared__ float dinv[M];                      //   200 B
    __shared__ struct Post {                       //  2932 B (phase union)
        float pbuf[16][15];
        union {
            struct { float z1[16][KTOP]; unsigned char ord[52]; } a;
            struct { float z2[352]; float d1[128]; } b;
        } u;
    } post;

    const int g = blockIdx.x;
    const int tid = threadIdx.x;
    const int nbase = g * M;
    const int ebase = g * EPG;
    const float* xg = x + (size_t)nbase * F_IN;

    // ---- init: degrees + zero the padded CSR arrays (pads contribute 0) ----
    if (tid < M) degi[tid] = 1;
    for (int idx = tid; idx < PADE; idx += NTHREADS) {
        csr_nrm[idx] = 0.f;
        csr_src[idx] = 0;
    }
    __syncthreads();
    for (int e = tid; e < EPG; e += NTHREADS) {
        int d = eidx[E_TOTAL + ebase + e] - nbase;
        atomicAdd(&degi[d], 1);
    }
    __syncthreads();
    // ---- dinv + padded-CSR offsets (wave-0 shuffle scan); cursor=degi ----
    if (tid < M) dinv[tid] = rsqrtf((float)degi[tid]);
    if (tid < 64) {
        int cnt  = (tid < M) ? (degi[tid] - 1) : 0;
        int cntp = (cnt + 3) & ~3;
        int incl = cntp;
#pragma unroll
        for (int off = 1; off < 64; off <<= 1) {
            int nv = __shfl_up(incl, off);
            if (tid >= off) incl += nv;
        }
        if (tid < M) {
            csr_off[tid] = (unsigned short)(incl - cntp);
            degi[tid] = incl - cntp;
        }
        if (tid == M - 1) csr_off[M] = (unsigned short)incl;
    }
    __syncthreads();
    // ---- CSR fill (by dst); re-read eidx (L2-hot) ----
    for (int e = tid; e < EPG; e += NTHREADS) {
        int s = eidx[ebase + e] - nbase;
        int d = eidx[E_TOTAL + ebase + e] - nbase;
        float nr = dinv[s] * dinv[d];
        int pos = atomicAdd(&degi[d], 1);
        csr_src[pos] = (unsigned char)s;
        csr_nrm[pos] = nr;
    }
    __syncthreads();

    // ---- layer 1: x[50,128] (global) @ W0 -> agg -> lat[:,0:32] ----
    gcn_matmul<F_IN>(xg, F_IN, W0, tbuf, tid);
    __syncthreads();
    gcn_agg(tbuf, b0, lat, 0, dinv, csr_off, csr_src, csr_nrm, tid);
    __syncthreads();
    // ---- layer 2 ----
    gcn_matmul<H>(&lat[0][0], LATS, W1, tbuf, tid);
    __syncthreads();
    gcn_agg(tbuf, b1, lat, 32, dinv, csr_off, csr_src, csr_nrm, tid);
    __syncthreads();
    // ---- layer 3 ----
    gcn_matmul<H>(&lat[0][32], LATS, W2, tbuf, tid);
    __syncthreads();
    gcn_agg(tbuf, b2, lat, 64, dinv, csr_off, csr_src, csr_nrm, tid);
    __syncthreads();
    // ---- layer 4 (H -> 1): exact tanhf (sort key) ----
    if (tid < M) {
        float acc = 0.f;
        for (int k = 0; k < H; k++) acc += lat[tid][64 + k] * W3[k];
        tbuf[tid][0] = acc;
    }
    __syncthreads();
    if (tid < M) {
        float acc = tbuf[tid][0] * dinv[tid] * dinv[tid];
        int e0 = csr_off[tid], e1 = csr_off[tid + 1];
        for (int e = e0; e < e1; e += 4) {
            unsigned sp = *(const unsigned*)(csr_src + e);
            float4 nr = *(const float4*)(csr_nrm + e);
            acc += tbuf[sp & 255][0] * nr.x + tbuf[(sp >> 8) & 255][0] * nr.y
                 + tbuf[(sp >> 16) & 255][0] * nr.z + tbuf[sp >> 24][0] * nr.w;
        }
        lat[tid][96] = tanhf(acc + b3[0]);
    }
    __syncthreads();

    // ---- sort-pool: stable descending rank over lat[:,96] ----
    if (tid < M) {
        float v = lat[tid][96];
        int r = 0;
        for (int jj = 0; jj < M; jj++) {
            float vj = lat[jj][96];
            r += (vj > v) || (vj == v && jj < tid);
        }
        post.u.a.ord[r] = (unsigned char)tid;
    }
    __syncthreads();

    // ---- Conv1d(1,16,97,stride 97) + ReLU (t=idx>>4: row broadcast) ----
    for (int idx = tid; idx < 16 * KTOP; idx += NTHREADS) {
        int t = idx >> 4, c = idx & 15;
        const float* row = lat[post.u.a.ord[t]];
        float acc = 0.f;
        for (int d = 0; d < DLAT; d++) acc += row[d] * C1w[c * DLAT + d];
        acc += C1b[c];
        post.u.a.z1[c][t] = fmaxf(acc, 0.f);
    }
    __syncthreads();

    // ---- MaxPool1d(2,2) -> pbuf (outside union) ----
    for (int idx = tid; idx < 16 * 15; idx += NTHREADS) {
        int c = idx / 15, t = idx - c * 15;
        post.pbuf[c][t] = fmaxf(post.u.a.z1[c][2 * t], post.u.a.z1[c][2 * t + 1]);
    }
    __syncthreads();

    // ---- Conv1d(16,32,5) + ReLU, flatten f = o*11 + t ----
    for (int idx = tid; idx < 352; idx += NTHREADS) {
        int o = idx / 11, t = idx - o * 11;
        float acc = C2b[o];
        for (int i = 0; i < 16; i++) {
#pragma unroll
            for (int k = 0; k < 5; k++)
                acc += post.pbuf[i][t + k] * C2w[(o * 16 + i) * 5 + k];
        }
        post.u.b.z2[idx] = fmaxf(acc, 0.f);
    }
    __syncthreads();

    // ---- Dense 352 -> 128 + ReLU ----
    if (tid < 128) {
        float acc = L1b[tid];
        for (int f = 0; f < 352; f++) acc += post.u.b.z2[f] * L1w[f * 128 + tid];
        post.u.b.d1[tid] = fmaxf(acc, 0.f);
    }
    __syncthreads();

    // ---- Dense 128 -> 1, wave-reduce ----
    if (tid < 64) {
        float v = post.u.b.d1[tid] * L2w[tid]
                + post.u.b.d1[tid + 64] * L2w[tid + 64];
#pragma unroll
        for (int off = 32; off >= 1; off >>= 1)
            v += __shfl_down(v, off);
        if (tid == 0) out[g] = v + L2b[0];
    }
}

extern "C" void kernel_launch(void* const* d_in, const int* in_sizes, int n_in,
                              void* d_out, int out_size, void* d_ws, size_t ws_size,
                              hipStream_t stream) {
    const float* x    = (const float*)d_in[0];
    const int*   eidx = (const int*)d_in[1];
    // d_in[2] (batch) unused: graphs are contiguous equal-size blocks
    dgcnn_kernel<<<NG, NTHREADS, 0, stream>>>(
        x, eidx,
        (const float*)d_in[3],  (const float*)d_in[4],
        (const float*)d_in[5],  (const float*)d_in[6],
        (const float*)d_in[7],  (const float*)d_in[8],
        (const float*)d_in[9],  (const float*)d_in[10],
        (const float*)d_in[11], (const float*)d_in[12],
        (const float*)d_in[13], (const float*)d_in[14],
        (const float*)d_in[15], (const float*)d_in[16],
        (const float*)d_in[17], (const float*)d_in[18],
        (float*)d_out);
}